// Round 2
// baseline (443.934 us; speedup 1.0000x reference)
//
#include <hip/hip_runtime.h>

// QuantizedLinear: out[M,N] = (rowquant(x) . W_q) * a_scale[M] * w_scale[N] + bias[N]
// M=8192, K=4096, N=4096.
// R2: GEMM -> BK=128 (32KB LDS, half the barriers), mfma_i32_32x32x32_i8,
//     XOR-swizzled LDS chunks (kills the 1.7e7 bank conflicts); quant+transpose fused.

typedef int   int32x4  __attribute__((ext_vector_type(4)));
typedef int   int32x16 __attribute__((ext_vector_type(16)));
typedef float floatx4  __attribute__((ext_vector_type(4)));

#define BM 128
#define BN 128
#define BK 128   // k-bytes per stage (i8)

__device__ __forceinline__ void async_copy16(const void* g, void* l) {
    __builtin_amdgcn_global_load_lds(
        (const __attribute__((address_space(1))) unsigned int*)g,
        (__attribute__((address_space(3))) unsigned int*)l,
        16, 0, 0);
}

__device__ __forceinline__ int quant1(float x, float s) {
    float q = rintf(x / s);               // true division: match np (x / a_scale)
    q = fminf(127.0f, fmaxf(-128.0f, q)); // np.clip(round, -128, 127)
    return (int)q;
}

// ---------------- kernel 1: fused prep ----------------
// blocks [0,M): per-row dynamic quant of x -> xq, ascale
// blocks [M, M + (N/64)*(K/64)): transpose+pack W_q int32[K,N] -> int8[N,K]
__global__ __launch_bounds__(256) void prep_kernel(
    const float* __restrict__ x, const int* __restrict__ Bq,
    signed char* __restrict__ xq, signed char* __restrict__ Bt,
    float* __restrict__ ascale, int M, int K, int N)
{
    __shared__ __align__(16) int shmem[64 * 17];
    const int t = threadIdx.x;
    const int b = (int)blockIdx.x;

    if (b < M) {
        // ---- quant path ----
        const int row = b;
        const float4* xr4 = (const float4*)(x + (size_t)row * K);
        float4 v[4];
        float mx = 0.0f;
#pragma unroll
        for (int i = 0; i < 4; ++i) {
            v[i] = xr4[t * 4 + i];
            mx = fmaxf(mx, fmaxf(fmaxf(fabsf(v[i].x), fabsf(v[i].y)),
                                 fmaxf(fabsf(v[i].z), fabsf(v[i].w))));
        }
#pragma unroll
        for (int off = 32; off > 0; off >>= 1)
            mx = fmaxf(mx, __shfl_xor(mx, off, 64));
        float* wmax = (float*)shmem;
        if ((t & 63) == 0) wmax[t >> 6] = mx;
        __syncthreads();
        mx = fmaxf(fmaxf(wmax[0], wmax[1]), fmaxf(wmax[2], wmax[3]));

        const float s = fmaxf(mx / 127.0f, 1e-8f);
        if (t == 0) ascale[row] = s;

        int out[4];
#pragma unroll
        for (int i = 0; i < 4; ++i) {
            const int b0 = quant1(v[i].x, s);
            const int b1 = quant1(v[i].y, s);
            const int b2 = quant1(v[i].z, s);
            const int b3 = quant1(v[i].w, s);
            out[i] = (b0 & 255) | ((b1 & 255) << 8) | ((b2 & 255) << 16) | ((b3 & 255) << 24);
        }
        *(int32x4*)(xq + (size_t)row * K + t * 16) = *(const int32x4*)out;
    } else {
        // ---- transpose+pack path ----
        const int tile = b - M;
        const int tiles_n = N >> 6;
        const int n0 = (tile % tiles_n) * 64;
        const int k0 = (tile / tiles_n) * 64;

        const int r = t >> 4;            // k-dword group 0..15 -> rows 4r..4r+3
        const int ncol = (t & 15) * 4;

        const int* src = Bq + (size_t)(k0 + 4 * r) * N + n0 + ncol;
        const int4 u0 = *(const int4*)(src);
        const int4 u1 = *(const int4*)(src + N);
        const int4 u2 = *(const int4*)(src + 2 * (size_t)N);
        const int4 u3 = *(const int4*)(src + 3 * (size_t)N);

        shmem[(ncol + 0) * 17 + r] = (u0.x & 255) | ((u1.x & 255) << 8) | ((u2.x & 255) << 16) | ((u3.x & 255) << 24);
        shmem[(ncol + 1) * 17 + r] = (u0.y & 255) | ((u1.y & 255) << 8) | ((u2.y & 255) << 16) | ((u3.y & 255) << 24);
        shmem[(ncol + 2) * 17 + r] = (u0.z & 255) | ((u1.z & 255) << 8) | ((u2.z & 255) << 16) | ((u3.z & 255) << 24);
        shmem[(ncol + 3) * 17 + r] = (u0.w & 255) | ((u1.w & 255) << 8) | ((u2.w & 255) << 16) | ((u3.w & 255) << 24);
        __syncthreads();

        const int nl = t >> 2, ch = t & 3;
        int o[4];
#pragma unroll
        for (int i = 0; i < 4; ++i) o[i] = shmem[nl * 17 + ch * 4 + i];
        *(int32x4*)(Bt + (size_t)(n0 + nl) * K + k0 + ch * 16) = *(const int32x4*)o;
    }
}

// ---------------- kernel 2: int8 GEMM + dequant epilogue ----------------
// A = xq [M,K] i8, B = Bt [N,K] i8 (k-contiguous). 128x128 C-tile, BK=128.
// 4 waves 2x2; wave tile 64x64 as 2x2 of mfma_i32_32x32x32_i8.
// LDS layout is XOR-chunk-swizzled: (row m, 16B chunk c) lives at
//   m*128 + (c ^ (m&7))*16   -- staged by permuting each thread's SOURCE chunk,
// since global_load_lds forces LDS dst = uniform + lane*16.
__global__ __launch_bounds__(256, 3) void gemm_i8_kernel(
    const signed char* __restrict__ Aq, const signed char* __restrict__ Bt,
    const float* __restrict__ ascale, const float* __restrict__ wscale,
    const float* __restrict__ bias, float* __restrict__ C,
    int M, int N, int K)
{
    __shared__ __align__(16) signed char As[BM * BK]; // 16 KB
    __shared__ __align__(16) signed char Bs[BN * BK]; // 16 KB

    const int t = threadIdx.x;
    const int lane = t & 63;
    const int w = t >> 6;
    const int wr = w >> 1, wc = w & 1;

    const int m0 = blockIdx.y * BM;
    const int n0 = blockIdx.x * BN;

    // staging: round r covers rows r*32..r*32+31; thread t -> row r*32+(t>>3),
    // stored chunk c'=t&7, fetched (global) chunk c = c' ^ (row&7).
    const int srow = t >> 3;                 // 0..31
    const int schunk = ((t & 7) ^ (srow & 7)) * 16;
    const signed char* gA = Aq + (size_t)(m0 + srow) * K + schunk;
    const signed char* gB = Bt + (size_t)(n0 + srow) * K + schunk;
    signed char* lA = As + t * 16;
    signed char* lB = Bs + t * 16;

    // fragment bases: lane holds A[m=base+ (lane&31)][k = kk*32 + (lane>>5)*16 + j]
    const int ml = lane & 31;
    const int half = lane >> 5;              // 0/1
    const int sw = ml & 7;                   // row&7 for swizzle (bases are %8==0)
    const signed char* fA0 = As + (wr * 64 + ml) * BK;
    const signed char* fA1 = fA0 + 32 * BK;
    const signed char* fB0 = Bs + (wc * 64 + ml) * BK;
    const signed char* fB1 = fB0 + 32 * BK;

    int32x16 acc[2][2] = {};

    for (int k0 = 0; k0 < K; k0 += BK) {
#pragma unroll
        for (int r = 0; r < 8; ++r)
            async_copy16(gA + k0 + (size_t)r * 32 * K, lA + r * 4096);
#pragma unroll
        for (int r = 0; r < 8; ++r)
            async_copy16(gB + k0 + (size_t)r * 32 * K, lB + r * 4096);
        __syncthreads();

#pragma unroll
        for (int kk = 0; kk < 4; ++kk) {
            const int chunk = kk * 2 + half;
            const int off = ((chunk ^ sw) * 16);
            int32x4 a0 = *(const int32x4*)(fA0 + off);
            int32x4 a1 = *(const int32x4*)(fA1 + off);
            int32x4 b0 = *(const int32x4*)(fB0 + off);
            int32x4 b1 = *(const int32x4*)(fB1 + off);
            acc[0][0] = __builtin_amdgcn_mfma_i32_32x32x32_i8(a0, b0, acc[0][0], 0, 0, 0);
            acc[0][1] = __builtin_amdgcn_mfma_i32_32x32x32_i8(a0, b1, acc[0][1], 0, 0, 0);
            acc[1][0] = __builtin_amdgcn_mfma_i32_32x32x32_i8(a1, b0, acc[1][0], 0, 0, 0);
            acc[1][1] = __builtin_amdgcn_mfma_i32_32x32x32_i8(a1, b1, acc[1][1], 0, 0, 0);
        }
        __syncthreads();
    }

    // epilogue: 32x32 C/D layout col=lane&31, row=(reg&3)+8*(reg>>2)+4*(lane>>5)
    const int rowoff = 4 * half;
#pragma unroll
    for (int j = 0; j < 2; ++j) {
        const int col = n0 + wc * 64 + j * 32 + ml;
        const float ws = wscale[col];
        const float bs = bias[col];
#pragma unroll
        for (int i = 0; i < 2; ++i) {
            const int rbase = m0 + wr * 64 + i * 32 + rowoff;
#pragma unroll
            for (int g = 0; g < 4; ++g) {
                const int rg = rbase + 8 * g;
                const floatx4 as4 = *(const floatx4*)(ascale + rg);
                float* cp = C + (size_t)rg * N + col;
#pragma unroll
                for (int rr = 0; rr < 4; ++rr) {
                    // match ref order: (c * a_scale) * w_scale + bias
                    cp[(size_t)rr * N] = ((float)acc[i][j][g * 4 + rr] * as4[rr]) * ws + bs;
                }
            }
        }
    }
}

extern "C" void kernel_launch(void* const* d_in, const int* in_sizes, int n_in,
                              void* d_out, int out_size, void* d_ws, size_t ws_size,
                              hipStream_t stream) {
    const float* x      = (const float*)d_in[0];
    const int*   wq     = (const int*)d_in[1];   // int8 values in int32 storage
    const float* wscale = (const float*)d_in[2];
    const float* bias   = (const float*)d_in[3];
    float* out          = (float*)d_out;

    const int N = in_sizes[2];
    const int K = in_sizes[1] / N;
    const int M = in_sizes[0] / K;

    // workspace: x_q [M*K] i8 | Bt [N*K] i8 | a_scale [M] f32
    char* ws = (char*)d_ws;
    signed char* xq = (signed char*)ws;
    signed char* bt = (signed char*)(ws + (size_t)M * K);
    float* ascale   = (float*)(ws + (size_t)M * K + (size_t)N * K);

    const int prep_blocks = M + (N / 64) * (K / 64);
    prep_kernel<<<prep_blocks, 256, 0, stream>>>(x, wq, xq, bt, ascale, M, K, N);
    gemm_i8_kernel<<<dim3(N / BN, M / BM), 256, 0, stream>>>(
        xq, bt, ascale, wscale, bias, out, M, N, K);
}

// Round 3
// 438.499 us; speedup vs baseline: 1.0124x; 1.0124x over previous
//
#include <hip/hip_runtime.h>

// QuantizedLinear: out[M,N] = (rowquant(x) . W_q) * a_scale[M] * w_scale[N] + bias[N]
// M=8192, K=4096, N=4096.
// R3: GEMM = R1 structure (BK=64, 16KB LDS, ~3 blocks/CU) but with
//     mfma_i32_32x32x32_i8 (4404 vs 3944 TOPS ceiling, half the issue slots).
//     4-chunk XOR swizzle keeps the 32-row fragment reads bank-balanced.
//     NOTE: SQ_LDS_BANK_CONFLICT ~1.678e7 here is intrinsic ds_read_b128
//     overhead (4 cyc/instr x 4.19e6 instrs), NOT a fixable layout conflict.

typedef int   int32x4  __attribute__((ext_vector_type(4)));
typedef int   int32x16 __attribute__((ext_vector_type(16)));
typedef float floatx4  __attribute__((ext_vector_type(4)));

#define BM 128
#define BN 128
#define BK 64

__device__ __forceinline__ void async_copy16(const void* g, void* l) {
    __builtin_amdgcn_global_load_lds(
        (const __attribute__((address_space(1))) unsigned int*)g,
        (__attribute__((address_space(3))) unsigned int*)l,
        16, 0, 0);
}

__device__ __forceinline__ int quant1(float x, float s) {
    float q = rintf(x / s);               // true division: match np (x / a_scale)
    q = fminf(127.0f, fmaxf(-128.0f, q)); // np.clip(round, -128, 127)
    return (int)q;
}

// ---------------- kernel 1: fused prep ----------------
// blocks [0,M): per-row dynamic quant of x -> xq, ascale
// blocks [M, M + (N/64)*(K/64)): transpose+pack W_q int32[K,N] -> int8[N,K]
__global__ __launch_bounds__(256) void prep_kernel(
    const float* __restrict__ x, const int* __restrict__ Bq,
    signed char* __restrict__ xq, signed char* __restrict__ Bt,
    float* __restrict__ ascale, int M, int K, int N)
{
    __shared__ __align__(16) int shmem[64 * 17];
    const int t = threadIdx.x;
    const int b = (int)blockIdx.x;

    if (b < M) {
        // ---- quant path: lane-contiguous float4 loads (1 KB/wave/instr) ----
        const int row = b;
        const float4* xr4 = (const float4*)(x + (size_t)row * K);
        float4 v[4];
        float mx = 0.0f;
#pragma unroll
        for (int i = 0; i < 4; ++i) {
            v[i] = xr4[i * 256 + t];
            mx = fmaxf(mx, fmaxf(fmaxf(fabsf(v[i].x), fabsf(v[i].y)),
                                 fmaxf(fabsf(v[i].z), fabsf(v[i].w))));
        }
#pragma unroll
        for (int off = 32; off > 0; off >>= 1)
            mx = fmaxf(mx, __shfl_xor(mx, off, 64));
        float* wmax = (float*)shmem;
        if ((t & 63) == 0) wmax[t >> 6] = mx;
        __syncthreads();
        mx = fmaxf(fmaxf(wmax[0], wmax[1]), fmaxf(wmax[2], wmax[3]));

        const float s = fmaxf(mx / 127.0f, 1e-8f);
        if (t == 0) ascale[row] = s;

        int* xqi = (int*)(xq + (size_t)row * K);
#pragma unroll
        for (int i = 0; i < 4; ++i) {
            const int b0 = quant1(v[i].x, s);
            const int b1 = quant1(v[i].y, s);
            const int b2 = quant1(v[i].z, s);
            const int b3 = quant1(v[i].w, s);
            xqi[i * 256 + t] =
                (b0 & 255) | ((b1 & 255) << 8) | ((b2 & 255) << 16) | ((b3 & 255) << 24);
        }
    } else {
        // ---- transpose+pack path ----
        const int tile = b - M;
        const int tiles_n = N >> 6;
        const int n0 = (tile % tiles_n) * 64;
        const int k0 = (tile / tiles_n) * 64;

        const int r = t >> 4;            // k-dword group 0..15 -> rows 4r..4r+3
        const int ncol = (t & 15) * 4;

        const int* src = Bq + (size_t)(k0 + 4 * r) * N + n0 + ncol;
        const int4 u0 = *(const int4*)(src);
        const int4 u1 = *(const int4*)(src + N);
        const int4 u2 = *(const int4*)(src + 2 * (size_t)N);
        const int4 u3 = *(const int4*)(src + 3 * (size_t)N);

        shmem[(ncol + 0) * 17 + r] = (u0.x & 255) | ((u1.x & 255) << 8) | ((u2.x & 255) << 16) | ((u3.x & 255) << 24);
        shmem[(ncol + 1) * 17 + r] = (u0.y & 255) | ((u1.y & 255) << 8) | ((u2.y & 255) << 16) | ((u3.y & 255) << 24);
        shmem[(ncol + 2) * 17 + r] = (u0.z & 255) | ((u1.z & 255) << 8) | ((u2.z & 255) << 16) | ((u3.z & 255) << 24);
        shmem[(ncol + 3) * 17 + r] = (u0.w & 255) | ((u1.w & 255) << 8) | ((u2.w & 255) << 16) | ((u3.w & 255) << 24);
        __syncthreads();

        const int nl = t >> 2, ch = t & 3;
        int o[4];
#pragma unroll
        for (int i = 0; i < 4; ++i) o[i] = shmem[nl * 17 + ch * 4 + i];
        *(int32x4*)(Bt + (size_t)(n0 + nl) * K + k0 + ch * 16) = *(const int32x4*)o;
    }
}

// ---------------- kernel 2: int8 GEMM + dequant epilogue ----------------
// A = xq [M,K] i8, B = Bt [N,K] i8 (k-contiguous). 128x128 C-tile, BK=64.
// 4 waves 2x2; wave tile 64x64 as 2x2 of mfma_i32_32x32x32_i8, 2 k-steps/stage.
// LDS chunk swizzle: (row m, 16B chunk c) stored at m*64 + (c ^ (m&3))*16 so
// the 32-row fragment reads cover all 32 banks (unswizzled covers only 16).
__global__ __launch_bounds__(256, 2) void gemm_i8_kernel(
    const signed char* __restrict__ Aq, const signed char* __restrict__ Bt,
    const float* __restrict__ ascale, const float* __restrict__ wscale,
    const float* __restrict__ bias, float* __restrict__ C,
    int M, int N, int K)
{
    __shared__ __align__(16) signed char As[BM * BK]; // 8 KB
    __shared__ __align__(16) signed char Bs[BN * BK]; // 8 KB

    const int t = threadIdx.x;
    const int lane = t & 63;
    const int w = t >> 6;
    const int wr = w >> 1, wc = w & 1;

    const int m0 = blockIdx.y * BM;
    const int n0 = blockIdx.x * BN;

    // staging: thread t -> row srow=t>>2 (and srow+64), stored chunk c'=t&3,
    // fetched global chunk c = c' ^ (srow&3). ((srow+64)&3)==(srow&3): consistent.
    const int srow = t >> 2;
    const int schunk = ((t & 3) ^ (srow & 3)) * 16;
    const signed char* gA0 = Aq + (size_t)(m0 + srow) * K + schunk;
    const signed char* gA1 = gA0 + (size_t)64 * K;
    const signed char* gB0 = Bt + (size_t)(n0 + srow) * K + schunk;
    const signed char* gB1 = gB0 + (size_t)64 * K;
    signed char* lA0 = As + t * 16;
    signed char* lA1 = lA0 + 4096;
    signed char* lB0 = Bs + t * 16;
    signed char* lB1 = lB0 + 4096;

    // fragments: lane holds op[m|n = base + (lane&31)][k = kk*32 + (lane>>5)*16 + j]
    const int ml = lane & 31;
    const int half = lane >> 5;
    const int sw = ml & 3;
    const signed char* fA0 = As + (wr * 64 + ml) * BK;
    const signed char* fA1 = fA0 + 32 * BK;
    const signed char* fB0 = Bs + (wc * 64 + ml) * BK;
    const signed char* fB1 = fB0 + 32 * BK;

    int32x16 acc[2][2] = {};

    for (int k0 = 0; k0 < K; k0 += BK) {
        async_copy16(gA0 + k0, lA0);
        async_copy16(gA1 + k0, lA1);
        async_copy16(gB0 + k0, lB0);
        async_copy16(gB1 + k0, lB1);
        __syncthreads();

#pragma unroll
        for (int kk = 0; kk < 2; ++kk) {
            const int off = (((kk * 2 + half) ^ sw) * 16);
            int32x4 a0 = *(const int32x4*)(fA0 + off);
            int32x4 a1 = *(const int32x4*)(fA1 + off);
            int32x4 b0 = *(const int32x4*)(fB0 + off);
            int32x4 b1 = *(const int32x4*)(fB1 + off);
            acc[0][0] = __builtin_amdgcn_mfma_i32_32x32x32_i8(a0, b0, acc[0][0], 0, 0, 0);
            acc[0][1] = __builtin_amdgcn_mfma_i32_32x32x32_i8(a0, b1, acc[0][1], 0, 0, 0);
            acc[1][0] = __builtin_amdgcn_mfma_i32_32x32x32_i8(a1, b0, acc[1][0], 0, 0, 0);
            acc[1][1] = __builtin_amdgcn_mfma_i32_32x32x32_i8(a1, b1, acc[1][1], 0, 0, 0);
        }
        __syncthreads();
    }

    // epilogue: 32x32 C/D layout col=lane&31, row=(reg&3)+8*(reg>>2)+4*(lane>>5)
    // (HW-verified in R2)
    const int rowoff = 4 * half;
#pragma unroll
    for (int j = 0; j < 2; ++j) {
        const int col = n0 + wc * 64 + j * 32 + ml;
        const float ws = wscale[col];
        const float bs = bias[col];
#pragma unroll
        for (int i = 0; i < 2; ++i) {
            const int rbase = m0 + wr * 64 + i * 32 + rowoff;
#pragma unroll
            for (int g = 0; g < 4; ++g) {
                const int rg = rbase + 8 * g;
                const floatx4 as4 = *(const floatx4*)(ascale + rg);
                float* cp = C + (size_t)rg * N + col;
#pragma unroll
                for (int rr = 0; rr < 4; ++rr) {
                    // match ref order: (c * a_scale) * w_scale + bias
                    cp[(size_t)rr * N] = ((float)acc[i][j][g * 4 + rr] * as4[rr]) * ws + bs;
                }
            }
        }
    }
}

extern "C" void kernel_launch(void* const* d_in, const int* in_sizes, int n_in,
                              void* d_out, int out_size, void* d_ws, size_t ws_size,
                              hipStream_t stream) {
    const float* x      = (const float*)d_in[0];
    const int*   wq     = (const int*)d_in[1];   // int8 values in int32 storage
    const float* wscale = (const float*)d_in[2];
    const float* bias   = (const float*)d_in[3];
    float* out          = (float*)d_out;

    const int N = in_sizes[2];
    const int K = in_sizes[1] / N;
    const int M = in_sizes[0] / K;

    // workspace: x_q [M*K] i8 | Bt [N*K] i8 | a_scale [M] f32
    char* ws = (char*)d_ws;
    signed char* xq = (signed char*)ws;
    signed char* bt = (signed char*)(ws + (size_t)M * K);
    float* ascale   = (float*)(ws + (size_t)M * K + (size_t)N * K);

    const int prep_blocks = M + (N / 64) * (K / 64);
    prep_kernel<<<prep_blocks, 256, 0, stream>>>(x, wq, xq, bt, ascale, M, K, N);
    gemm_i8_kernel<<<dim3(N / BN, M / BM), 256, 0, stream>>>(
        xq, bt, ascale, wscale, bias, out, M, N, K);
}